// Round 8
// baseline (394.409 us; speedup 1.0000x reference)
//
#include <hip/hip_runtime.h>

#define BB 32
#define L_MAXX 4096
#define DD 512
#define T_MAXX 2048
#define MAXW 9   // max window rows: floor(L_MAX/T_min)+1 = 4096/512+1

typedef float f32x4 __attribute__((ext_vector_type(4)));

// Kernel 1: valid_len[b] = number of zero entries in padding_mask[b,:].
// Mask is materialized as int32: 4096 int32 per batch = 16 KB.
__global__ __launch_bounds__(256) void valid_len_kernel(
    const int* __restrict__ mask, int* __restrict__ vlen) {
    __shared__ int s;
    const int b = blockIdx.x;
    const int tid = threadIdx.x;
    if (tid == 0) s = 0;
    __syncthreads();
    const int4* m = reinterpret_cast<const int4*>(mask + (size_t)b * L_MAXX);
    int cnt = 0;
    #pragma unroll
    for (int j = 0; j < 4; ++j) {
        int4 v = m[tid + j * 256];
        cnt += (v.x != 0) + (v.y != 0) + (v.z != 0) + (v.w != 0);
    }
    atomicAdd(&s, cnt);
    __syncthreads();
    if (tid == 0) vlen[b] = L_MAXX - s;   // count of valid (False) positions
}

// Kernel 2: one WAVE (64 lanes) per output row t; lane covers 8 floats
// (two float4 loads) => 64*8 = 512 = D. Window gather fully unrolled
// (cnt <= 9, wave-uniform predicates) so all loads issue back-to-back.
__global__ __launch_bounds__(256) void area_resample_kernel(
    const float* __restrict__ x,
    const int* __restrict__ finallength,
    const int* __restrict__ vlen,
    float* __restrict__ out,
    float* __restrict__ out_mask) {
    const int blk = blockIdx.x;
    const int b = blk >> 9;                                // 512 blocks per batch
    const int t = ((blk & 511) << 2) | (threadIdx.x >> 6); // 4 waves = 4 rows/block
    const int lane = threadIdx.x & 63;

    const int T = finallength[b];
    const int L = vlen[b];

    f32x4 a0 = (f32x4)(0.f);
    f32x4 a1 = (f32x4)(0.f);
    float inv = 0.f;
    if (t < T) {
        const unsigned uT = (unsigned)T, uL = (unsigned)L;
        const unsigned start = ((unsigned)t * uL) / uT;
        const unsigned end   = ((unsigned)(t + 1) * uL + uT - 1u) / uT;  // ceil
        const unsigned cnt   = end - start;                // >= 1 since L >= T
        const float* base = x + ((size_t)b * L_MAXX + start) * DD + lane * 8;

        f32x4 v[MAXW], w[MAXW];
        #pragma unroll
        for (int j = 0; j < MAXW; ++j) {
            if ((unsigned)j < cnt) {
                v[j] = *reinterpret_cast<const f32x4*>(base + (size_t)j * DD);
                w[j] = *reinterpret_cast<const f32x4*>(base + (size_t)j * DD + 4);
            } else {
                v[j] = (f32x4)(0.f);
                w[j] = (f32x4)(0.f);
            }
        }
        #pragma unroll
        for (int j = 0; j < MAXW; ++j) {
            a0 += v[j];
            a1 += w[j];
        }
        inv = 1.0f / (float)cnt;
    }
    a0 *= inv;
    a1 *= inv;

    float* orow = out + ((size_t)b * T_MAXX + t) * DD + lane * 8;
    __builtin_nontemporal_store(a0, reinterpret_cast<f32x4*>(orow));
    __builtin_nontemporal_store(a1, reinterpret_cast<f32x4*>(orow + 4));
    if (lane == 0) {
        out_mask[(size_t)b * T_MAXX + t] = (t < T) ? 0.0f : 1.0f;
    }
}

extern "C" void kernel_launch(void* const* d_in, const int* in_sizes, int n_in,
                              void* d_out, int out_size, void* d_ws, size_t ws_size,
                              hipStream_t stream) {
    const float* x = (const float*)d_in[0];
    const int* finallength = (const int*)d_in[1];
    const int* mask = (const int*)d_in[2];
    // d_in[3] = max_out_len scalar (always 2048 here) — compiled in as T_MAXX.

    float* out = (float*)d_out;
    float* out_mask = out + (size_t)BB * T_MAXX * DD;
    int* vlen = (int*)d_ws;

    valid_len_kernel<<<BB, 256, 0, stream>>>(mask, vlen);
    area_resample_kernel<<<BB * (T_MAXX / 4), 256, 0, stream>>>(
        x, finallength, vlen, out, out_mask);
}

// Round 10
// 388.774 us; speedup vs baseline: 1.0145x; 1.0145x over previous
//
#include <hip/hip_runtime.h>

#define BB 32
#define L_MAXX 4096
#define DD 512
#define T_MAXX 2048
#define MAXW 9   // max window rows: floor(L_MAX/T_min)+1 = 4096/512+1

typedef float f32x4 __attribute__((ext_vector_type(4)));

// Kernel 1: valid_len[b] = number of zero entries in padding_mask[b,:].
// Mask is materialized as int32: 4096 int32 per batch = 16 KB.
__global__ __launch_bounds__(256) void valid_len_kernel(
    const int* __restrict__ mask, int* __restrict__ vlen) {
    __shared__ int s;
    const int b = blockIdx.x;
    const int tid = threadIdx.x;
    if (tid == 0) s = 0;
    __syncthreads();
    const int4* m = reinterpret_cast<const int4*>(mask + (size_t)b * L_MAXX);
    int cnt = 0;
    #pragma unroll
    for (int j = 0; j < 4; ++j) {
        int4 v = m[tid + j * 256];
        cnt += (v.x != 0) + (v.y != 0) + (v.z != 0) + (v.w != 0);
    }
    atomicAdd(&s, cnt);
    __syncthreads();
    if (tid == 0) vlen[b] = L_MAXX - s;   // count of valid (False) positions
}

// Kernel 2: one WAVE per output row t. Lane covers floats [lane*4, lane*4+4)
// and [256+lane*4, ...): every load/store instruction is a dense, contiguous
// 1 KB wave transaction (64 lanes x 16 B) — no stride-32B interleave, so NT
// stores write-combine cleanly. XCD-chunked block swizzle keeps adjacent t
// (which share a boundary input row) on the same XCD's L2.
__global__ __launch_bounds__(256) void area_resample_kernel(
    const float* __restrict__ x,
    const int* __restrict__ finallength,
    const int* __restrict__ vlen,
    float* __restrict__ out,
    float* __restrict__ out_mask) {
    // bijective XCD swizzle: grid = 16384 = 8 * 2048
    const int blk = (blockIdx.x & 7) * 2048 + (blockIdx.x >> 3);
    const int b = blk >> 9;                                // 512 blocks per batch
    const int t = ((blk & 511) << 2) | (threadIdx.x >> 6); // 4 waves = 4 rows/block
    const int lane = threadIdx.x & 63;

    const int T = finallength[b];
    const int L = vlen[b];

    f32x4 a0 = (f32x4)(0.f);
    f32x4 a1 = (f32x4)(0.f);
    float inv = 0.f;
    if (t < T) {
        const unsigned uT = (unsigned)T, uL = (unsigned)L;
        const unsigned start = ((unsigned)t * uL) / uT;
        const unsigned end   = ((unsigned)(t + 1) * uL + uT - 1u) / uT;  // ceil
        const unsigned cnt   = end - start;                // >= 1 since L >= T
        const float* base = x + ((size_t)b * L_MAXX + start) * DD + lane * 4;

        f32x4 v[MAXW], w[MAXW];
        #pragma unroll
        for (int j = 0; j < MAXW; ++j) {
            if ((unsigned)j < cnt) {
                v[j] = *reinterpret_cast<const f32x4*>(base + (size_t)j * DD);
                w[j] = *reinterpret_cast<const f32x4*>(base + (size_t)j * DD + 256);
            } else {
                v[j] = (f32x4)(0.f);
                w[j] = (f32x4)(0.f);
            }
        }
        #pragma unroll
        for (int j = 0; j < MAXW; ++j) {
            a0 += v[j];
            a1 += w[j];
        }
        inv = 1.0f / (float)cnt;
    }
    a0 *= inv;
    a1 *= inv;

    float* orow = out + ((size_t)b * T_MAXX + t) * DD + lane * 4;
    __builtin_nontemporal_store(a0, reinterpret_cast<f32x4*>(orow));
    __builtin_nontemporal_store(a1, reinterpret_cast<f32x4*>(orow + 256));
    if (lane == 0) {
        out_mask[(size_t)b * T_MAXX + t] = (t < T) ? 0.0f : 1.0f;
    }
}

extern "C" void kernel_launch(void* const* d_in, const int* in_sizes, int n_in,
                              void* d_out, int out_size, void* d_ws, size_t ws_size,
                              hipStream_t stream) {
    const float* x = (const float*)d_in[0];
    const int* finallength = (const int*)d_in[1];
    const int* mask = (const int*)d_in[2];
    // d_in[3] = max_out_len scalar (always 2048 here) — compiled in as T_MAXX.

    float* out = (float*)d_out;
    float* out_mask = out + (size_t)BB * T_MAXX * DD;
    int* vlen = (int*)d_ws;

    valid_len_kernel<<<BB, 256, 0, stream>>>(mask, vlen);
    area_resample_kernel<<<BB * (T_MAXX / 4), 256, 0, stream>>>(
        x, finallength, vlen, out, out_mask);
}